// Round 3
// baseline (665.075 us; speedup 1.0000x reference)
//
#include <hip/hip_runtime.h>

// GCN 2-layer, pull-based: CSR by dst (counting sort) + gather, no float atomics.
// hs = (A @ W) * dinv[row]  (GEMM epilogue scale)
// out[d] = dinv[d] * (sum_{in(d)} hs[s] + hs[d]) + b   [+ relu for layer 1]

// ---------------- degree / dinv ----------------

__global__ void indeg_k(const int* __restrict__ dst, int* __restrict__ indeg, int E) {
    int i = blockIdx.x * blockDim.x + threadIdx.x;
    if (i < E) atomicAdd(&indeg[dst[i]], 1);
}

__global__ void dinv_k(const int* __restrict__ indeg, float* __restrict__ dinv, int n) {
    int i = blockIdx.x * blockDim.x + threadIdx.x;
    if (i < n) dinv[i] = rsqrtf(1.0f + (float)indeg[i]);  // +1 self-loop
}

// ---------------- exclusive scan (3-pass, 1024 elems/block) ----------------

__global__ void scan1_k(const int* __restrict__ in, int* __restrict__ out,
                        int* __restrict__ bsums, int n) {
    __shared__ int lds[256];
    int t = threadIdx.x;
    int base = blockIdx.x * 1024 + t * 4;
    int v0 = 0, v1 = 0, v2 = 0, v3 = 0;
    if (base + 0 < n) v0 = in[base + 0];
    if (base + 1 < n) v1 = in[base + 1];
    if (base + 2 < n) v2 = in[base + 2];
    if (base + 3 < n) v3 = in[base + 3];
    lds[t] = v0 + v1 + v2 + v3;
    __syncthreads();
    for (int off = 1; off < 256; off <<= 1) {
        int x = (t >= off) ? lds[t - off] : 0;
        __syncthreads();
        lds[t] += x;
        __syncthreads();
    }
    int run = (t > 0) ? lds[t - 1] : 0;
    if (t == 255) bsums[blockIdx.x] = lds[255];
    if (base + 0 < n) { out[base + 0] = run; run += v0; }
    if (base + 1 < n) { out[base + 1] = run; run += v1; }
    if (base + 2 < n) { out[base + 2] = run; run += v2; }
    if (base + 3 < n) { out[base + 3] = run; run += v3; }
}

__global__ void scan2_k(int* __restrict__ bsums, int nb) {
    if (threadIdx.x == 0 && blockIdx.x == 0) {
        int run = 0;
        for (int i = 0; i < nb; ++i) { int v = bsums[i]; bsums[i] = run; run += v; }
    }
}

__global__ void scan3_k(int* __restrict__ out, const int* __restrict__ bsums, int n) {
    int i = blockIdx.x * blockDim.x + threadIdx.x;
    if (i < n) out[i] += bsums[i >> 10];
}

// ---------------- CSR fill (row_start mutates into row_end) ----------------

__global__ void fill_k(const int* __restrict__ src, const int* __restrict__ dst,
                       int* __restrict__ cur, int* __restrict__ ssrc, int E) {
    int i = blockIdx.x * blockDim.x + threadIdx.x;
    if (i < E) {
        int d = dst[i];
        int p = atomicAdd(&cur[d], 1);
        ssrc[p] = src[i];
    }
}

// ---------------- tiled fp32 GEMM: [M,128] @ [128,BN] -> [M,BN] * dinv[row] ---
// BM=64, BK=16, 256 threads; thread (tx,ty) computes rows ty*4..+3,
// cols tx*4..+3 (and 64+tx*4..+3 when BN==128). Double-buffered LDS,
// global->reg prefetch of chunk k+1 before computing chunk k.

template <int BN>
__launch_bounds__(256, 4)
__global__ void gemm_tiled_k(const float* __restrict__ A, const float* __restrict__ W,
                             const float* __restrict__ dinv, float* __restrict__ C, int M) {
    constexpr int BM = 64, BK = 16, KI = 128 / BK;
    __shared__ float As[2][BK][BM + 4];   // k-major, padded for b128 column reads
    __shared__ float Bs[2][BK][BN];

    const int t = threadIdx.x;
    const int tx = t & 15;
    const int ty = t >> 4;
    const int r0 = blockIdx.x * BM;

    // A staging coords: one float4 per thread
    const int ar = t >> 2;          // 0..63 row within tile
    const int ak = (t & 3) * 4;     // k offset within chunk
    const int arow = (r0 + ar < M) ? (r0 + ar) : (M - 1);

    // W staging coords
    // BN=128: 2 float4/thread: rows t/32 and t/32+8, col (t%32)*4
    // BN=64 : 1 float4/thread: row t/16, col (t%16)*4
    const int br0 = (BN == 128) ? (t >> 5) : (t >> 4);
    const int bc0 = (BN == 128) ? ((t & 31) * 4) : ((t & 15) * 4);

    float4 aR, bR0, bR1;

    // prologue: load chunk 0
    aR = *(const float4*)&A[(size_t)arow * 128 + ak];
    bR0 = *(const float4*)&W[(size_t)br0 * BN + bc0];
    if (BN == 128) bR1 = *(const float4*)&W[(size_t)(br0 + 8) * BN + bc0];

    int buf = 0;
    {
        *(float*)&As[buf][ak + 0][ar] = aR.x;
        *(float*)&As[buf][ak + 1][ar] = aR.y;
        *(float*)&As[buf][ak + 2][ar] = aR.z;
        *(float*)&As[buf][ak + 3][ar] = aR.w;
        *(float4*)&Bs[buf][br0][bc0] = bR0;
        if (BN == 128) *(float4*)&Bs[buf][br0 + 8][bc0] = bR1;
    }
    __syncthreads();

    float acc0[4][4], acc1[4][4];
#pragma unroll
    for (int r = 0; r < 4; ++r)
#pragma unroll
        for (int c = 0; c < 4; ++c) { acc0[r][c] = 0.f; acc1[r][c] = 0.f; }

#pragma unroll 1
    for (int it = 0; it < KI; ++it) {
        const int k0n = (it + 1) * BK;
        if (it + 1 < KI) {
            aR = *(const float4*)&A[(size_t)arow * 128 + k0n + ak];
            bR0 = *(const float4*)&W[(size_t)(k0n + br0) * BN + bc0];
            if (BN == 128) bR1 = *(const float4*)&W[(size_t)(k0n + br0 + 8) * BN + bc0];
        }
#pragma unroll
        for (int k = 0; k < BK; ++k) {
            float4 av = *(const float4*)&As[buf][k][ty * 4];
            float4 b0 = *(const float4*)&Bs[buf][k][tx * 4];
            float a_[4] = {av.x, av.y, av.z, av.w};
            float b0_[4] = {b0.x, b0.y, b0.z, b0.w};
            if (BN == 128) {
                float4 b1 = *(const float4*)&Bs[buf][k][64 + tx * 4];
                float b1_[4] = {b1.x, b1.y, b1.z, b1.w};
#pragma unroll
                for (int r = 0; r < 4; ++r)
#pragma unroll
                    for (int c = 0; c < 4; ++c) {
                        acc0[r][c] = fmaf(a_[r], b0_[c], acc0[r][c]);
                        acc1[r][c] = fmaf(a_[r], b1_[c], acc1[r][c]);
                    }
            } else {
#pragma unroll
                for (int r = 0; r < 4; ++r)
#pragma unroll
                    for (int c = 0; c < 4; ++c)
                        acc0[r][c] = fmaf(a_[r], b0_[c], acc0[r][c]);
            }
        }
        if (it + 1 < KI) {
            int nb = buf ^ 1;
            *(float*)&As[nb][ak + 0][ar] = aR.x;
            *(float*)&As[nb][ak + 1][ar] = aR.y;
            *(float*)&As[nb][ak + 2][ar] = aR.z;
            *(float*)&As[nb][ak + 3][ar] = aR.w;
            *(float4*)&Bs[nb][br0][bc0] = bR0;
            if (BN == 128) *(float4*)&Bs[nb][br0 + 8][bc0] = bR1;
            __syncthreads();
            buf = nb;
        }
    }

    // epilogue: scale by dinv[row], store
#pragma unroll
    for (int r = 0; r < 4; ++r) {
        int row = r0 + ty * 4 + r;
        if (row < M) {
            float s = dinv[row];
            float4 st;
            st.x = acc0[r][0] * s; st.y = acc0[r][1] * s;
            st.z = acc0[r][2] * s; st.w = acc0[r][3] * s;
            *(float4*)&C[(size_t)row * BN + tx * 4] = st;
            if (BN == 128) {
                float4 s2;
                s2.x = acc1[r][0] * s; s2.y = acc1[r][1] * s;
                s2.z = acc1[r][2] * s; s2.w = acc1[r][3] * s;
                *(float4*)&C[(size_t)row * BN + 64 + tx * 4] = s2;
            }
        }
    }
}

// ---------------- pull gather: one wave per node ----------------
// o[d] = dinv[d] * (sum_{in(d)} hs[s] + hs[d]) + bias   [+relu]

template <int D, bool RELU>
__global__ void gather_k(const float* __restrict__ hs, const int* __restrict__ ssrc,
                         const int* __restrict__ rend, const int* __restrict__ indeg,
                         const float* __restrict__ dinv, const float* __restrict__ bias,
                         float* __restrict__ o, int N) {
    int node = (int)((blockIdx.x * blockDim.x + threadIdx.x) >> 6);
    int lane = threadIdx.x & 63;
    if (node >= N) return;

    int end = rend[node];            // post-fill: row_end
    int start = end - indeg[node];
    float dv = dinv[node];

    if (D == 128) {
        const int c = 2 * lane;
        float2 acc = *(const float2*)&hs[(size_t)node * 128 + c];  // self loop
        int j = start;
        for (; j + 1 < end; j += 2) {
            int s0 = ssrc[j], s1 = ssrc[j + 1];
            float2 a = *(const float2*)&hs[(size_t)s0 * 128 + c];
            float2 b = *(const float2*)&hs[(size_t)s1 * 128 + c];
            acc.x += a.x + b.x;
            acc.y += a.y + b.y;
        }
        if (j < end) {
            int s0 = ssrc[j];
            float2 a = *(const float2*)&hs[(size_t)s0 * 128 + c];
            acc.x += a.x;
            acc.y += a.y;
        }
        float2 bb = *(const float2*)&bias[c];
        acc.x = acc.x * dv + bb.x;
        acc.y = acc.y * dv + bb.y;
        if (RELU) {
            acc.x = fmaxf(acc.x, 0.f);
            acc.y = fmaxf(acc.y, 0.f);
        }
        *(float2*)&o[(size_t)node * 128 + c] = acc;
    } else {
        float acc = hs[(size_t)node * 64 + lane];
        int j = start;
        for (; j + 1 < end; j += 2) {
            int s0 = ssrc[j], s1 = ssrc[j + 1];
            float a = hs[(size_t)s0 * 64 + lane];
            float b = hs[(size_t)s1 * 64 + lane];
            acc += a + b;
        }
        if (j < end) acc += hs[(size_t)ssrc[j] * 64 + lane];
        acc = acc * dv + bias[lane];
        if (RELU) acc = fmaxf(acc, 0.f);
        o[(size_t)node * 64 + lane] = acc;
    }
}

// ---------------- launcher ----------------

extern "C" void kernel_launch(void* const* d_in, const int* in_sizes, int n_in,
                              void* d_out, int out_size, void* d_ws, size_t ws_size,
                              hipStream_t stream) {
    const float* x  = (const float*)d_in[0];
    const int*   ei = (const int*)d_in[1];
    const float* W1 = (const float*)d_in[2];
    const float* b1 = (const float*)d_in[3];
    const float* W2 = (const float*)d_in[4];
    const float* b2 = (const float*)d_in[5];
    float* out = (float*)d_out;

    const int N = in_sizes[0] / 128;
    const int E = in_sizes[1] / 2;
    const int* esrc = ei;
    const int* edst = ei + E;

    // workspace layout
    int* indeg = (int*)d_ws;                    // N
    int* rs    = indeg + N;                     // N (row_start -> row_end after fill)
    int* bsums = rs + N;                        // 64
    int* ssrc  = bsums + 64;                    // E
    float* dinv = (float*)(ssrc + E);           // N
    float* hs1  = dinv + N;                     // N*128 (reused as hs2: N*64)
    float* g1   = hs1 + (size_t)N * 128;        // N*128
    float* hs2  = hs1;

    const int nb = (N + 1023) / 1024;

    // degree + dinv
    hipMemsetAsync(indeg, 0, (size_t)N * 4, stream);
    hipLaunchKernelGGL(indeg_k, dim3((E + 255) / 256), dim3(256), 0, stream, edst, indeg, E);
    hipLaunchKernelGGL(dinv_k, dim3((N + 255) / 256), dim3(256), 0, stream, indeg, dinv, N);

    // CSR build: exclusive scan of indeg -> rs, then fill (rs mutates to row_end)
    hipLaunchKernelGGL(scan1_k, dim3(nb), dim3(256), 0, stream, indeg, rs, bsums, N);
    hipLaunchKernelGGL(scan2_k, dim3(1), dim3(64), 0, stream, bsums, nb);
    hipLaunchKernelGGL(scan3_k, dim3((N + 255) / 256), dim3(256), 0, stream, rs, bsums, N);
    hipLaunchKernelGGL(fill_k, dim3((E + 255) / 256), dim3(256), 0, stream, esrc, edst, rs, ssrc, E);

    // layer 1: hs1 = (x@W1)*dinv ; g1 = relu(dinv*(gather+self) + b1)
    hipLaunchKernelGGL((gemm_tiled_k<128>), dim3((N + 63) / 64), dim3(256), 0, stream,
                       x, W1, dinv, hs1, N);
    hipLaunchKernelGGL((gather_k<128, true>), dim3((N + 3) / 4), dim3(256), 0, stream,
                       hs1, ssrc, rs, indeg, dinv, b1, g1, N);

    // layer 2: hs2 = (g1@W2)*dinv ; out = dinv*(gather+self) + b2
    hipLaunchKernelGGL((gemm_tiled_k<64>), dim3((N + 63) / 64), dim3(256), 0, stream,
                       g1, W2, dinv, hs2, N);
    hipLaunchKernelGGL((gather_k<64, false>), dim3((N + 3) / 4), dim3(256), 0, stream,
                       hs2, ssrc, rs, indeg, dinv, b2, out, N);
}

// Round 4
// 333.924 us; speedup vs baseline: 1.9917x; 1.9917x over previous
//
#include <hip/hip_runtime.h>

// GCN 2-layer, pull-based: CSR by dst (counting sort) + gather, no float atomics.
// hs = (A @ W) * dinv[row]  (GEMM epilogue scale)
// out[d] = dinv[d] * (sum_{in(d)} hs[s] + hs[d]) + b   [+ relu for layer 1]

// ---------------- degree / dinv ----------------

__global__ void indeg_k(const int* __restrict__ dst, int* __restrict__ indeg, int E) {
    int i = blockIdx.x * blockDim.x + threadIdx.x;
    if (i < E) atomicAdd(&indeg[dst[i]], 1);
}

__global__ void dinv_k(const int* __restrict__ indeg, float* __restrict__ dinv, int n) {
    int i = blockIdx.x * blockDim.x + threadIdx.x;
    if (i < n) dinv[i] = rsqrtf(1.0f + (float)indeg[i]);  // +1 self-loop
}

// ---------------- exclusive scan (3-pass, 1024 elems/block) ----------------

__global__ void scan1_k(const int* __restrict__ in, int* __restrict__ out,
                        int* __restrict__ bsums, int n) {
    __shared__ int lds[256];
    int t = threadIdx.x;
    int base = blockIdx.x * 1024 + t * 4;
    int v0 = 0, v1 = 0, v2 = 0, v3 = 0;
    if (base + 0 < n) v0 = in[base + 0];
    if (base + 1 < n) v1 = in[base + 1];
    if (base + 2 < n) v2 = in[base + 2];
    if (base + 3 < n) v3 = in[base + 3];
    lds[t] = v0 + v1 + v2 + v3;
    __syncthreads();
    for (int off = 1; off < 256; off <<= 1) {
        int x = (t >= off) ? lds[t - off] : 0;
        __syncthreads();
        lds[t] += x;
        __syncthreads();
    }
    int run = (t > 0) ? lds[t - 1] : 0;
    if (t == 255) bsums[blockIdx.x] = lds[255];
    if (base + 0 < n) { out[base + 0] = run; run += v0; }
    if (base + 1 < n) { out[base + 1] = run; run += v1; }
    if (base + 2 < n) { out[base + 2] = run; run += v2; }
    if (base + 3 < n) { out[base + 3] = run; run += v3; }
}

__global__ void scan2_k(int* __restrict__ bsums, int nb) {
    if (threadIdx.x == 0 && blockIdx.x == 0) {
        int run = 0;
        for (int i = 0; i < nb; ++i) { int v = bsums[i]; bsums[i] = run; run += v; }
    }
}

__global__ void scan3_k(int* __restrict__ out, const int* __restrict__ bsums, int n) {
    int i = blockIdx.x * blockDim.x + threadIdx.x;
    if (i < n) out[i] += bsums[i >> 10];
}

// ---------------- CSR fill (row_start mutates into row_end) ----------------

__global__ void fill_k(const int* __restrict__ src, const int* __restrict__ dst,
                       int* __restrict__ cur, int* __restrict__ ssrc, int E) {
    int i = blockIdx.x * blockDim.x + threadIdx.x;
    if (i < E) {
        int d = dst[i];
        int p = atomicAdd(&cur[d], 1);
        ssrc[p] = src[i];
    }
}

// ---------------- tiled fp32 GEMM: [M,128] @ [128,BN] -> [M,BN] * dinv[row] ---
// BM=64, BK=16, 256 threads; thread (tx,ty) computes rows ty*4..+3,
// cols tx*4..+3 (and 64+tx*4..+3 when BN==128). Double-buffered LDS,
// global->reg prefetch of chunk k+1 before computing chunk k.
// NOTE: no min-occupancy pledge — (256,4) forced VGPR=64 and spilled the
// accumulators to scratch (R3: 771 MB WRITE_SIZE). Registers > occupancy here.

template <int BN>
__launch_bounds__(256)
__global__ void gemm_tiled_k(const float* __restrict__ A, const float* __restrict__ W,
                             const float* __restrict__ dinv, float* __restrict__ C, int M) {
    constexpr int BM = 64, BK = 16, KI = 128 / BK;
    __shared__ float As[2][BK][BM + 4];   // k-major, padded
    __shared__ float Bs[2][BK][BN];

    const int t = threadIdx.x;
    const int tx = t & 15;
    const int ty = t >> 4;
    const int r0 = blockIdx.x * BM;

    // A staging coords: one float4 per thread
    const int ar = t >> 2;          // 0..63 row within tile
    const int ak = (t & 3) * 4;     // k offset within chunk
    const int arow = (r0 + ar < M) ? (r0 + ar) : (M - 1);

    // W staging coords
    const int br0 = (BN == 128) ? (t >> 5) : (t >> 4);
    const int bc0 = (BN == 128) ? ((t & 31) * 4) : ((t & 15) * 4);

    float4 aR, bR0, bR1;

    aR = *(const float4*)&A[(size_t)arow * 128 + ak];
    bR0 = *(const float4*)&W[(size_t)br0 * BN + bc0];
    if (BN == 128) bR1 = *(const float4*)&W[(size_t)(br0 + 8) * BN + bc0];

    int buf = 0;
    {
        As[buf][ak + 0][ar] = aR.x;
        As[buf][ak + 1][ar] = aR.y;
        As[buf][ak + 2][ar] = aR.z;
        As[buf][ak + 3][ar] = aR.w;
        *(float4*)&Bs[buf][br0][bc0] = bR0;
        if (BN == 128) *(float4*)&Bs[buf][br0 + 8][bc0] = bR1;
    }
    __syncthreads();

    float acc0[4][4], acc1[4][4];
#pragma unroll
    for (int r = 0; r < 4; ++r)
#pragma unroll
        for (int c = 0; c < 4; ++c) { acc0[r][c] = 0.f; acc1[r][c] = 0.f; }

#pragma unroll 1
    for (int it = 0; it < KI; ++it) {
        const int k0n = (it + 1) * BK;
        if (it + 1 < KI) {
            aR = *(const float4*)&A[(size_t)arow * 128 + k0n + ak];
            bR0 = *(const float4*)&W[(size_t)(k0n + br0) * BN + bc0];
            if (BN == 128) bR1 = *(const float4*)&W[(size_t)(k0n + br0 + 8) * BN + bc0];
        }
#pragma unroll
        for (int k = 0; k < BK; ++k) {
            float4 av = *(const float4*)&As[buf][k][ty * 4];
            float4 b0 = *(const float4*)&Bs[buf][k][tx * 4];
            float a_[4] = {av.x, av.y, av.z, av.w};
            float b0_[4] = {b0.x, b0.y, b0.z, b0.w};
            if (BN == 128) {
                float4 b1 = *(const float4*)&Bs[buf][k][64 + tx * 4];
                float b1_[4] = {b1.x, b1.y, b1.z, b1.w};
#pragma unroll
                for (int r = 0; r < 4; ++r)
#pragma unroll
                    for (int c = 0; c < 4; ++c) {
                        acc0[r][c] = fmaf(a_[r], b0_[c], acc0[r][c]);
                        acc1[r][c] = fmaf(a_[r], b1_[c], acc1[r][c]);
                    }
            } else {
#pragma unroll
                for (int r = 0; r < 4; ++r)
#pragma unroll
                    for (int c = 0; c < 4; ++c)
                        acc0[r][c] = fmaf(a_[r], b0_[c], acc0[r][c]);
            }
        }
        if (it + 1 < KI) {
            int nb = buf ^ 1;
            As[nb][ak + 0][ar] = aR.x;
            As[nb][ak + 1][ar] = aR.y;
            As[nb][ak + 2][ar] = aR.z;
            As[nb][ak + 3][ar] = aR.w;
            *(float4*)&Bs[nb][br0][bc0] = bR0;
            if (BN == 128) *(float4*)&Bs[nb][br0 + 8][bc0] = bR1;
            __syncthreads();
            buf = nb;
        }
    }

#pragma unroll
    for (int r = 0; r < 4; ++r) {
        int row = r0 + ty * 4 + r;
        if (row < M) {
            float s = dinv[row];
            float4 st;
            st.x = acc0[r][0] * s; st.y = acc0[r][1] * s;
            st.z = acc0[r][2] * s; st.w = acc0[r][3] * s;
            *(float4*)&C[(size_t)row * BN + tx * 4] = st;
            if (BN == 128) {
                float4 s2;
                s2.x = acc1[r][0] * s; s2.y = acc1[r][1] * s;
                s2.z = acc1[r][2] * s; s2.w = acc1[r][3] * s;
                *(float4*)&C[(size_t)row * BN + 64 + tx * 4] = s2;
            }
        }
    }
}

// ---------------- pull gather: one wave per node ----------------
// Index loads: one coalesced per-lane load covers 64 edges, __shfl broadcasts;
// 4-edge unroll keeps 4 independent feature loads in flight.

template <int D, bool RELU>
__global__ void gather_k(const float* __restrict__ hs, const int* __restrict__ ssrc,
                         const int* __restrict__ rend, const int* __restrict__ indeg,
                         const float* __restrict__ dinv, const float* __restrict__ bias,
                         float* __restrict__ o, int N) {
    int node = (int)((blockIdx.x * blockDim.x + threadIdx.x) >> 6);
    int lane = threadIdx.x & 63;
    if (node >= N) return;

    int end = rend[node];            // post-fill: row_end
    int deg = indeg[node];
    int start = end - deg;
    float dv = dinv[node];

    if (D == 128) {
        const int c = 2 * lane;
        const float* hp = hs + c;
        float2 acc = *(const float2*)&hp[(size_t)node * 128];  // self loop
        for (int base = start; base < end; base += 64) {
            int n = end - base;
            if (n > 64) n = 64;
            int idx = ssrc[(base + lane < end) ? (base + lane) : base];
            int e = 0;
            for (; e + 4 <= n; e += 4) {
                int s0 = __shfl(idx, e + 0);
                int s1 = __shfl(idx, e + 1);
                int s2 = __shfl(idx, e + 2);
                int s3 = __shfl(idx, e + 3);
                float2 a0 = *(const float2*)&hp[(size_t)s0 * 128];
                float2 a1 = *(const float2*)&hp[(size_t)s1 * 128];
                float2 a2 = *(const float2*)&hp[(size_t)s2 * 128];
                float2 a3 = *(const float2*)&hp[(size_t)s3 * 128];
                acc.x += (a0.x + a1.x) + (a2.x + a3.x);
                acc.y += (a0.y + a1.y) + (a2.y + a3.y);
            }
            for (; e < n; ++e) {
                int s0 = __shfl(idx, e);
                float2 a0 = *(const float2*)&hp[(size_t)s0 * 128];
                acc.x += a0.x;
                acc.y += a0.y;
            }
        }
        float2 bb = *(const float2*)&bias[c];
        acc.x = acc.x * dv + bb.x;
        acc.y = acc.y * dv + bb.y;
        if (RELU) {
            acc.x = fmaxf(acc.x, 0.f);
            acc.y = fmaxf(acc.y, 0.f);
        }
        *(float2*)&o[(size_t)node * 128 + c] = acc;
    } else {
        const float* hp = hs + lane;
        float acc = hp[(size_t)node * 64];
        for (int base = start; base < end; base += 64) {
            int n = end - base;
            if (n > 64) n = 64;
            int idx = ssrc[(base + lane < end) ? (base + lane) : base];
            int e = 0;
            for (; e + 4 <= n; e += 4) {
                int s0 = __shfl(idx, e + 0);
                int s1 = __shfl(idx, e + 1);
                int s2 = __shfl(idx, e + 2);
                int s3 = __shfl(idx, e + 3);
                float a0 = hp[(size_t)s0 * 64];
                float a1 = hp[(size_t)s1 * 64];
                float a2 = hp[(size_t)s2 * 64];
                float a3 = hp[(size_t)s3 * 64];
                acc += (a0 + a1) + (a2 + a3);
            }
            for (; e < n; ++e) {
                int s0 = __shfl(idx, e);
                acc += hp[(size_t)s0 * 64];
            }
        }
        acc = acc * dv + bias[lane];
        if (RELU) acc = fmaxf(acc, 0.f);
        o[(size_t)node * 64 + lane] = acc;
    }
}

// ---------------- launcher ----------------

extern "C" void kernel_launch(void* const* d_in, const int* in_sizes, int n_in,
                              void* d_out, int out_size, void* d_ws, size_t ws_size,
                              hipStream_t stream) {
    const float* x  = (const float*)d_in[0];
    const int*   ei = (const int*)d_in[1];
    const float* W1 = (const float*)d_in[2];
    const float* b1 = (const float*)d_in[3];
    const float* W2 = (const float*)d_in[4];
    const float* b2 = (const float*)d_in[5];
    float* out = (float*)d_out;

    const int N = in_sizes[0] / 128;
    const int E = in_sizes[1] / 2;
    const int* esrc = ei;
    const int* edst = ei + E;

    // workspace layout
    int* indeg = (int*)d_ws;                    // N
    int* rs    = indeg + N;                     // N (row_start -> row_end after fill)
    int* bsums = rs + N;                        // 64
    int* ssrc  = bsums + 64;                    // E
    float* dinv = (float*)(ssrc + E);           // N
    float* hs1  = dinv + N;                     // N*128 (reused as hs2: N*64)
    float* g1   = hs1 + (size_t)N * 128;        // N*128
    float* hs2  = hs1;

    const int nb = (N + 1023) / 1024;

    // degree + dinv
    hipMemsetAsync(indeg, 0, (size_t)N * 4, stream);
    hipLaunchKernelGGL(indeg_k, dim3((E + 255) / 256), dim3(256), 0, stream, edst, indeg, E);
    hipLaunchKernelGGL(dinv_k, dim3((N + 255) / 256), dim3(256), 0, stream, indeg, dinv, N);

    // CSR build
    hipLaunchKernelGGL(scan1_k, dim3(nb), dim3(256), 0, stream, indeg, rs, bsums, N);
    hipLaunchKernelGGL(scan2_k, dim3(1), dim3(64), 0, stream, bsums, nb);
    hipLaunchKernelGGL(scan3_k, dim3((N + 255) / 256), dim3(256), 0, stream, rs, bsums, N);
    hipLaunchKernelGGL(fill_k, dim3((E + 255) / 256), dim3(256), 0, stream, esrc, edst, rs, ssrc, E);

    // layer 1
    hipLaunchKernelGGL((gemm_tiled_k<128>), dim3((N + 63) / 64), dim3(256), 0, stream,
                       x, W1, dinv, hs1, N);
    hipLaunchKernelGGL((gather_k<128, true>), dim3((N + 3) / 4), dim3(256), 0, stream,
                       hs1, ssrc, rs, indeg, dinv, b1, g1, N);

    // layer 2
    hipLaunchKernelGGL((gemm_tiled_k<64>), dim3((N + 63) / 64), dim3(256), 0, stream,
                       g1, W2, dinv, hs2, N);
    hipLaunchKernelGGL((gather_k<64, false>), dim3((N + 3) / 4), dim3(256), 0, stream,
                       hs2, ssrc, rs, indeg, dinv, b2, out, N);
}

// Round 5
// 291.169 us; speedup vs baseline: 2.2842x; 1.1468x over previous
//
#include <hip/hip_runtime.h>
#include <hip/hip_fp16.h>

// GCN 2-layer, pull-based CSR gather. Dense intermediates (hs) stored fp16
// to halve the random-gather byte traffic (the measured bottleneck, R4).
// hs = (A @ W) * dinv[row]  (GEMM epilogue scale + fp16 convert)
// out[d] = dinv[d] * (sum_{in(d)} hs[s] + hs[d]) + b   [+ relu for layer 1]

typedef _Float16 half_t;
typedef _Float16 half2_t __attribute__((ext_vector_type(2)));
typedef _Float16 half4_t __attribute__((ext_vector_type(4)));

// ---------------- degree ----------------

__global__ void indeg_k(const int* __restrict__ dst, int* __restrict__ indeg, int E) {
    int i = blockIdx.x * blockDim.x + threadIdx.x;
    if (i < E) atomicAdd(&indeg[dst[i]], 1);
}

// ---------------- exclusive scan (1024 elems/block) + dinv fused ----------------

__global__ void scan1_k(const int* __restrict__ in, int* __restrict__ out,
                        int* __restrict__ bsums, float* __restrict__ dinv, int n) {
    __shared__ int lds[256];
    int t = threadIdx.x;
    int base = blockIdx.x * 1024 + t * 4;
    int v0 = 0, v1 = 0, v2 = 0, v3 = 0;
    if (base + 0 < n) v0 = in[base + 0];
    if (base + 1 < n) v1 = in[base + 1];
    if (base + 2 < n) v2 = in[base + 2];
    if (base + 3 < n) v3 = in[base + 3];
    // fused dinv = rsqrt(1 + indeg)
    if (base + 0 < n) dinv[base + 0] = rsqrtf(1.0f + (float)v0);
    if (base + 1 < n) dinv[base + 1] = rsqrtf(1.0f + (float)v1);
    if (base + 2 < n) dinv[base + 2] = rsqrtf(1.0f + (float)v2);
    if (base + 3 < n) dinv[base + 3] = rsqrtf(1.0f + (float)v3);
    lds[t] = v0 + v1 + v2 + v3;
    __syncthreads();
    for (int off = 1; off < 256; off <<= 1) {
        int x = (t >= off) ? lds[t - off] : 0;
        __syncthreads();
        lds[t] += x;
        __syncthreads();
    }
    int run = (t > 0) ? lds[t - 1] : 0;
    if (t == 255) bsums[blockIdx.x] = lds[255];
    if (base + 0 < n) { out[base + 0] = run; run += v0; }
    if (base + 1 < n) { out[base + 1] = run; run += v1; }
    if (base + 2 < n) { out[base + 2] = run; run += v2; }
    if (base + 3 < n) { out[base + 3] = run; run += v3; }
}

// scan of <=64 block sums done redundantly per block (replaces serial scan2)
__global__ void scan3_k(int* __restrict__ out, const int* __restrict__ bsums,
                        int nb, int n) {
    __shared__ int pre[64];
    int t = threadIdx.x;
    if (t < 64) {
        int v = (t < nb) ? bsums[t] : 0;
#pragma unroll
        for (int off = 1; off < 64; off <<= 1) {
            int u = __shfl_up(v, off);
            if (t >= off) v += u;
        }
        pre[t] = v;                 // inclusive scan
    }
    __syncthreads();
    int i = blockIdx.x * blockDim.x + t;
    if (i < n) {
        int b = i >> 10;
        out[i] += (b > 0) ? pre[b - 1] : 0;
    }
}

// ---------------- CSR fill (row_start mutates into row_end) ----------------

__global__ void fill_k(const int* __restrict__ src, const int* __restrict__ dst,
                       int* __restrict__ cur, int* __restrict__ ssrc, int E) {
    int i = blockIdx.x * blockDim.x + threadIdx.x;
    if (i < E) {
        int d = dst[i];
        int p = atomicAdd(&cur[d], 1);
        ssrc[p] = src[i];
    }
}

// ---------------- tiled fp32 GEMM -> fp16 out: [M,128]@[128,BN] * dinv[row] ---
// BM=64, BK=16, 256 threads, 4x4(+4x4) micro-tile, double-buffered LDS.
// No min-occupancy pledge (R3: (256,4) spilled accumulators to scratch).

template <int BN>
__launch_bounds__(256)
__global__ void gemm_tiled_k(const float* __restrict__ A, const float* __restrict__ W,
                             const float* __restrict__ dinv, half_t* __restrict__ C, int M) {
    constexpr int BM = 64, BK = 16, KI = 128 / BK;
    __shared__ float As[2][BK][BM + 4];
    __shared__ float Bs[2][BK][BN];

    const int t = threadIdx.x;
    const int tx = t & 15;
    const int ty = t >> 4;
    const int r0 = blockIdx.x * BM;

    const int ar = t >> 2;
    const int ak = (t & 3) * 4;
    const int arow = (r0 + ar < M) ? (r0 + ar) : (M - 1);

    const int br0 = (BN == 128) ? (t >> 5) : (t >> 4);
    const int bc0 = (BN == 128) ? ((t & 31) * 4) : ((t & 15) * 4);

    float4 aR, bR0, bR1;

    aR = *(const float4*)&A[(size_t)arow * 128 + ak];
    bR0 = *(const float4*)&W[(size_t)br0 * BN + bc0];
    if (BN == 128) bR1 = *(const float4*)&W[(size_t)(br0 + 8) * BN + bc0];

    int buf = 0;
    {
        As[buf][ak + 0][ar] = aR.x;
        As[buf][ak + 1][ar] = aR.y;
        As[buf][ak + 2][ar] = aR.z;
        As[buf][ak + 3][ar] = aR.w;
        *(float4*)&Bs[buf][br0][bc0] = bR0;
        if (BN == 128) *(float4*)&Bs[buf][br0 + 8][bc0] = bR1;
    }
    __syncthreads();

    float acc0[4][4], acc1[4][4];
#pragma unroll
    for (int r = 0; r < 4; ++r)
#pragma unroll
        for (int c = 0; c < 4; ++c) { acc0[r][c] = 0.f; acc1[r][c] = 0.f; }

#pragma unroll 1
    for (int it = 0; it < KI; ++it) {
        const int k0n = (it + 1) * BK;
        if (it + 1 < KI) {
            aR = *(const float4*)&A[(size_t)arow * 128 + k0n + ak];
            bR0 = *(const float4*)&W[(size_t)(k0n + br0) * BN + bc0];
            if (BN == 128) bR1 = *(const float4*)&W[(size_t)(k0n + br0 + 8) * BN + bc0];
        }
#pragma unroll
        for (int k = 0; k < BK; ++k) {
            float4 av = *(const float4*)&As[buf][k][ty * 4];
            float4 b0 = *(const float4*)&Bs[buf][k][tx * 4];
            float a_[4] = {av.x, av.y, av.z, av.w};
            float b0_[4] = {b0.x, b0.y, b0.z, b0.w};
            if (BN == 128) {
                float4 b1 = *(const float4*)&Bs[buf][k][64 + tx * 4];
                float b1_[4] = {b1.x, b1.y, b1.z, b1.w};
#pragma unroll
                for (int r = 0; r < 4; ++r)
#pragma unroll
                    for (int c = 0; c < 4; ++c) {
                        acc0[r][c] = fmaf(a_[r], b0_[c], acc0[r][c]);
                        acc1[r][c] = fmaf(a_[r], b1_[c], acc1[r][c]);
                    }
            } else {
#pragma unroll
                for (int r = 0; r < 4; ++r)
#pragma unroll
                    for (int c = 0; c < 4; ++c)
                        acc0[r][c] = fmaf(a_[r], b0_[c], acc0[r][c]);
            }
        }
        if (it + 1 < KI) {
            int nb = buf ^ 1;
            As[nb][ak + 0][ar] = aR.x;
            As[nb][ak + 1][ar] = aR.y;
            As[nb][ak + 2][ar] = aR.z;
            As[nb][ak + 3][ar] = aR.w;
            *(float4*)&Bs[nb][br0][bc0] = bR0;
            if (BN == 128) *(float4*)&Bs[nb][br0 + 8][bc0] = bR1;
            __syncthreads();
            buf = nb;
        }
    }

#pragma unroll
    for (int r = 0; r < 4; ++r) {
        int row = r0 + ty * 4 + r;
        if (row < M) {
            float s = dinv[row];
            half4_t p;
            p.x = (half_t)(acc0[r][0] * s); p.y = (half_t)(acc0[r][1] * s);
            p.z = (half_t)(acc0[r][2] * s); p.w = (half_t)(acc0[r][3] * s);
            *(half4_t*)&C[(size_t)row * BN + tx * 4] = p;
            if (BN == 128) {
                half4_t q;
                q.x = (half_t)(acc1[r][0] * s); q.y = (half_t)(acc1[r][1] * s);
                q.z = (half_t)(acc1[r][2] * s); q.w = (half_t)(acc1[r][3] * s);
                *(half4_t*)&C[(size_t)row * BN + 64 + tx * 4] = q;
            }
        }
    }
}

// ---------------- pull gather (fp16 features, fp32 accumulate) ----------------

template <int D, bool RELU>
__global__ void gather_k(const half_t* __restrict__ hs, const int* __restrict__ ssrc,
                         const int* __restrict__ rend, const int* __restrict__ indeg,
                         const float* __restrict__ dinv, const float* __restrict__ bias,
                         float* __restrict__ o, int N) {
    int node = (int)((blockIdx.x * blockDim.x + threadIdx.x) >> 6);
    int lane = threadIdx.x & 63;
    if (node >= N) return;

    int end = rend[node];            // post-fill: row_end
    int deg = indeg[node];
    int start = end - deg;
    float dv = dinv[node];

    if (D == 128) {
        const half_t* hp = hs + 2 * lane;
        half2_t sv = *(const half2_t*)&hp[(size_t)node * 128];   // self loop
        float2 acc;
        acc.x = (float)sv.x;
        acc.y = (float)sv.y;
        for (int base = start; base < end; base += 64) {
            int n = end - base;
            if (n > 64) n = 64;
            int idx = ssrc[(base + lane < end) ? (base + lane) : base];
            int e = 0;
            for (; e + 4 <= n; e += 4) {
                int s0 = __shfl(idx, e + 0);
                int s1 = __shfl(idx, e + 1);
                int s2 = __shfl(idx, e + 2);
                int s3 = __shfl(idx, e + 3);
                half2_t a0 = *(const half2_t*)&hp[(size_t)s0 * 128];
                half2_t a1 = *(const half2_t*)&hp[(size_t)s1 * 128];
                half2_t a2 = *(const half2_t*)&hp[(size_t)s2 * 128];
                half2_t a3 = *(const half2_t*)&hp[(size_t)s3 * 128];
                acc.x += ((float)a0.x + (float)a1.x) + ((float)a2.x + (float)a3.x);
                acc.y += ((float)a0.y + (float)a1.y) + ((float)a2.y + (float)a3.y);
            }
            for (; e < n; ++e) {
                int s0 = __shfl(idx, e);
                half2_t a0 = *(const half2_t*)&hp[(size_t)s0 * 128];
                acc.x += (float)a0.x;
                acc.y += (float)a0.y;
            }
        }
        float2 bb = *(const float2*)&bias[2 * lane];
        acc.x = acc.x * dv + bb.x;
        acc.y = acc.y * dv + bb.y;
        if (RELU) {
            acc.x = fmaxf(acc.x, 0.f);
            acc.y = fmaxf(acc.y, 0.f);
        }
        *(float2*)&o[(size_t)node * 128 + 2 * lane] = acc;
    } else {
        const half_t* hp = hs + lane;
        float acc = (float)hp[(size_t)node * 64];
        for (int base = start; base < end; base += 64) {
            int n = end - base;
            if (n > 64) n = 64;
            int idx = ssrc[(base + lane < end) ? (base + lane) : base];
            int e = 0;
            for (; e + 4 <= n; e += 4) {
                int s0 = __shfl(idx, e + 0);
                int s1 = __shfl(idx, e + 1);
                int s2 = __shfl(idx, e + 2);
                int s3 = __shfl(idx, e + 3);
                float a0 = (float)hp[(size_t)s0 * 64];
                float a1 = (float)hp[(size_t)s1 * 64];
                float a2 = (float)hp[(size_t)s2 * 64];
                float a3 = (float)hp[(size_t)s3 * 64];
                acc += (a0 + a1) + (a2 + a3);
            }
            for (; e < n; ++e) {
                int s0 = __shfl(idx, e);
                acc += (float)hp[(size_t)s0 * 64];
            }
        }
        acc = acc * dv + bias[lane];
        if (RELU) acc = fmaxf(acc, 0.f);
        o[(size_t)node * 64 + lane] = acc;
    }
}

// ---------------- launcher ----------------

extern "C" void kernel_launch(void* const* d_in, const int* in_sizes, int n_in,
                              void* d_out, int out_size, void* d_ws, size_t ws_size,
                              hipStream_t stream) {
    const float* x  = (const float*)d_in[0];
    const int*   ei = (const int*)d_in[1];
    const float* W1 = (const float*)d_in[2];
    const float* b1 = (const float*)d_in[3];
    const float* W2 = (const float*)d_in[4];
    const float* b2 = (const float*)d_in[5];
    float* out = (float*)d_out;

    const int N = in_sizes[0] / 128;
    const int E = in_sizes[1] / 2;
    const int* esrc = ei;
    const int* edst = ei + E;

    // workspace layout
    int* indeg = (int*)d_ws;                    // N
    int* rs    = indeg + N;                     // N (row_start -> row_end after fill)
    int* bsums = rs + N;                        // 64
    int* ssrc  = bsums + 64;                    // E
    float* dinv = (float*)(ssrc + E);           // N
    half_t* hs1 = (half_t*)(dinv + N);          // N*128 fp16 (reused as hs2: N*64)
    float* g1   = (float*)(hs1 + (size_t)N * 128); // N*128 fp32
    half_t* hs2 = hs1;

    const int nb = (N + 1023) / 1024;

    // degree + dinv + CSR
    hipMemsetAsync(indeg, 0, (size_t)N * 4, stream);
    hipLaunchKernelGGL(indeg_k, dim3((E + 255) / 256), dim3(256), 0, stream, edst, indeg, E);
    hipLaunchKernelGGL(scan1_k, dim3(nb), dim3(256), 0, stream, indeg, rs, bsums, dinv, N);
    hipLaunchKernelGGL(scan3_k, dim3((N + 255) / 256), dim3(256), 0, stream, rs, bsums, nb, N);
    hipLaunchKernelGGL(fill_k, dim3((E + 255) / 256), dim3(256), 0, stream, esrc, edst, rs, ssrc, E);

    // layer 1
    hipLaunchKernelGGL((gemm_tiled_k<128>), dim3((N + 63) / 64), dim3(256), 0, stream,
                       x, W1, dinv, hs1, N);
    hipLaunchKernelGGL((gather_k<128, true>), dim3((N + 3) / 4), dim3(256), 0, stream,
                       hs1, ssrc, rs, indeg, dinv, b1, g1, N);

    // layer 2
    hipLaunchKernelGGL((gemm_tiled_k<64>), dim3((N + 63) / 64), dim3(256), 0, stream,
                       g1, W2, dinv, hs2, N);
    hipLaunchKernelGGL((gather_k<64, false>), dim3((N + 3) / 4), dim3(256), 0, stream,
                       hs2, ssrc, rs, indeg, dinv, b2, out, N);
}

// Round 6
// 278.896 us; speedup vs baseline: 2.3847x; 1.0440x over previous
//
#include <hip/hip_runtime.h>
#include <hip/hip_fp16.h>

// GCN 2-layer, pull-based CSR gather. fp16 dense intermediates.
// R6: uint16 CSR indices (halve scatter write-amp), fill fused with gemm1
// (independent work, one launch), int4-vectorized degree count.

typedef _Float16 half_t;
typedef _Float16 half2_t __attribute__((ext_vector_type(2)));
typedef _Float16 half4_t __attribute__((ext_vector_type(4)));

// ---------------- degree (int4-vectorized atomics) ----------------

__global__ void indeg_k(const int* __restrict__ dst, int* __restrict__ indeg, int E) {
    int i = blockIdx.x * blockDim.x + threadIdx.x;
    int E4 = E >> 2;
    if (i < E4) {
        int4 d = ((const int4*)dst)[i];
        atomicAdd(&indeg[d.x], 1);
        atomicAdd(&indeg[d.y], 1);
        atomicAdd(&indeg[d.z], 1);
        atomicAdd(&indeg[d.w], 1);
    }
    int r = (E4 << 2) + i;
    if (r < E) atomicAdd(&indeg[dst[r]], 1);
}

// ---------------- exclusive scan (1024 elems/block) + dinv fused ----------------

__global__ void scan1_k(const int* __restrict__ in, int* __restrict__ out,
                        int* __restrict__ bsums, float* __restrict__ dinv, int n) {
    __shared__ int lds[256];
    int t = threadIdx.x;
    int base = blockIdx.x * 1024 + t * 4;
    int v0 = 0, v1 = 0, v2 = 0, v3 = 0;
    if (base + 0 < n) v0 = in[base + 0];
    if (base + 1 < n) v1 = in[base + 1];
    if (base + 2 < n) v2 = in[base + 2];
    if (base + 3 < n) v3 = in[base + 3];
    if (base + 0 < n) dinv[base + 0] = rsqrtf(1.0f + (float)v0);
    if (base + 1 < n) dinv[base + 1] = rsqrtf(1.0f + (float)v1);
    if (base + 2 < n) dinv[base + 2] = rsqrtf(1.0f + (float)v2);
    if (base + 3 < n) dinv[base + 3] = rsqrtf(1.0f + (float)v3);
    lds[t] = v0 + v1 + v2 + v3;
    __syncthreads();
    for (int off = 1; off < 256; off <<= 1) {
        int x = (t >= off) ? lds[t - off] : 0;
        __syncthreads();
        lds[t] += x;
        __syncthreads();
    }
    int run = (t > 0) ? lds[t - 1] : 0;
    if (t == 255) bsums[blockIdx.x] = lds[255];
    if (base + 0 < n) { out[base + 0] = run; run += v0; }
    if (base + 1 < n) { out[base + 1] = run; run += v1; }
    if (base + 2 < n) { out[base + 2] = run; run += v2; }
    if (base + 3 < n) { out[base + 3] = run; run += v3; }
}

// scan of <=64 block sums done redundantly per block
__global__ void scan3_k(int* __restrict__ out, const int* __restrict__ bsums,
                        int nb, int n) {
    __shared__ int pre[64];
    int t = threadIdx.x;
    if (t < 64) {
        int v = (t < nb) ? bsums[t] : 0;
#pragma unroll
        for (int off = 1; off < 64; off <<= 1) {
            int u = __shfl_up(v, off);
            if (t >= off) v += u;
        }
        pre[t] = v;
    }
    __syncthreads();
    int i = blockIdx.x * blockDim.x + t;
    if (i < n) {
        int b = i >> 10;
        out[i] += (b > 0) ? pre[b - 1] : 0;
    }
}

// ---------------- tiled fp32 GEMM body -> fp16 out ----------------
// BM=64, BK=16, 256 threads, 4x4(+4x4) micro-tile, double-buffered LDS.
// No min-occupancy pledge (R3: (256,4) spilled accumulators to scratch).

template <int BN>
__device__ __forceinline__ void gemm_body(const float* __restrict__ A,
                                          const float* __restrict__ W,
                                          const float* __restrict__ dinv,
                                          half_t* __restrict__ C, int M, int r0) {
    constexpr int BM = 64, BK = 16, KI = 128 / BK;
    __shared__ float As[2][BK][BM + 4];
    __shared__ float Bs[2][BK][BN];

    const int t = threadIdx.x;
    const int tx = t & 15;
    const int ty = t >> 4;

    const int ar = t >> 2;
    const int ak = (t & 3) * 4;
    const int arow = (r0 + ar < M) ? (r0 + ar) : (M - 1);

    const int br0 = (BN == 128) ? (t >> 5) : (t >> 4);
    const int bc0 = (BN == 128) ? ((t & 31) * 4) : ((t & 15) * 4);

    float4 aR, bR0, bR1;

    aR = *(const float4*)&A[(size_t)arow * 128 + ak];
    bR0 = *(const float4*)&W[(size_t)br0 * BN + bc0];
    if (BN == 128) bR1 = *(const float4*)&W[(size_t)(br0 + 8) * BN + bc0];

    int buf = 0;
    {
        As[buf][ak + 0][ar] = aR.x;
        As[buf][ak + 1][ar] = aR.y;
        As[buf][ak + 2][ar] = aR.z;
        As[buf][ak + 3][ar] = aR.w;
        *(float4*)&Bs[buf][br0][bc0] = bR0;
        if (BN == 128) *(float4*)&Bs[buf][br0 + 8][bc0] = bR1;
    }
    __syncthreads();

    float acc0[4][4], acc1[4][4];
#pragma unroll
    for (int r = 0; r < 4; ++r)
#pragma unroll
        for (int c = 0; c < 4; ++c) { acc0[r][c] = 0.f; acc1[r][c] = 0.f; }

#pragma unroll 1
    for (int it = 0; it < KI; ++it) {
        const int k0n = (it + 1) * BK;
        if (it + 1 < KI) {
            aR = *(const float4*)&A[(size_t)arow * 128 + k0n + ak];
            bR0 = *(const float4*)&W[(size_t)(k0n + br0) * BN + bc0];
            if (BN == 128) bR1 = *(const float4*)&W[(size_t)(k0n + br0 + 8) * BN + bc0];
        }
#pragma unroll
        for (int k = 0; k < BK; ++k) {
            float4 av = *(const float4*)&As[buf][k][ty * 4];
            float4 b0 = *(const float4*)&Bs[buf][k][tx * 4];
            float a_[4] = {av.x, av.y, av.z, av.w};
            float b0_[4] = {b0.x, b0.y, b0.z, b0.w};
            if (BN == 128) {
                float4 b1 = *(const float4*)&Bs[buf][k][64 + tx * 4];
                float b1_[4] = {b1.x, b1.y, b1.z, b1.w};
#pragma unroll
                for (int r = 0; r < 4; ++r)
#pragma unroll
                    for (int c = 0; c < 4; ++c) {
                        acc0[r][c] = fmaf(a_[r], b0_[c], acc0[r][c]);
                        acc1[r][c] = fmaf(a_[r], b1_[c], acc1[r][c]);
                    }
            } else {
#pragma unroll
                for (int r = 0; r < 4; ++r)
#pragma unroll
                    for (int c = 0; c < 4; ++c)
                        acc0[r][c] = fmaf(a_[r], b0_[c], acc0[r][c]);
            }
        }
        if (it + 1 < KI) {
            int nb = buf ^ 1;
            As[nb][ak + 0][ar] = aR.x;
            As[nb][ak + 1][ar] = aR.y;
            As[nb][ak + 2][ar] = aR.z;
            As[nb][ak + 3][ar] = aR.w;
            *(float4*)&Bs[nb][br0][bc0] = bR0;
            if (BN == 128) *(float4*)&Bs[nb][br0 + 8][bc0] = bR1;
            __syncthreads();
            buf = nb;
        }
    }

#pragma unroll
    for (int r = 0; r < 4; ++r) {
        int row = r0 + ty * 4 + r;
        if (row < M) {
            float s = dinv[row];
            half4_t p;
            p.x = (half_t)(acc0[r][0] * s); p.y = (half_t)(acc0[r][1] * s);
            p.z = (half_t)(acc0[r][2] * s); p.w = (half_t)(acc0[r][3] * s);
            *(half4_t*)&C[(size_t)row * BN + tx * 4] = p;
            if (BN == 128) {
                half4_t q;
                q.x = (half_t)(acc1[r][0] * s); q.y = (half_t)(acc1[r][1] * s);
                q.z = (half_t)(acc1[r][2] * s); q.w = (half_t)(acc1[r][3] * s);
                *(half4_t*)&C[(size_t)row * BN + 64 + tx * 4] = q;
            }
        }
    }
}

template <int BN>
__launch_bounds__(256)
__global__ void gemm_tiled_k(const float* __restrict__ A, const float* __restrict__ W,
                             const float* __restrict__ dinv, half_t* __restrict__ C, int M) {
    gemm_body<BN>(A, W, dinv, C, M, blockIdx.x * 64);
}

// ---------------- fused: gemm1 blocks + CSR-fill blocks (independent) -------

template <int BN, typename IDX>
__launch_bounds__(256)
__global__ void gemm_fill_k(const float* __restrict__ A, const float* __restrict__ W,
                            const float* __restrict__ dinv, half_t* __restrict__ C, int M,
                            int Ggemm,
                            const int* __restrict__ esrc, const int* __restrict__ edst,
                            int* __restrict__ cur, IDX* __restrict__ ssrc, int E) {
    int b = blockIdx.x;
    if (b < Ggemm) {
        gemm_body<BN>(A, W, dinv, C, M, b * 64);
    } else {
        int i = (b - Ggemm) * 512 + threadIdx.x;   // 2 edges per thread
        if (i < E) {
            int d = edst[i];
            int p = atomicAdd(&cur[d], 1);
            ssrc[p] = (IDX)esrc[i];
        }
        int j = i + 256;
        if (j < E) {
            int d = edst[j];
            int p = atomicAdd(&cur[d], 1);
            ssrc[p] = (IDX)esrc[j];
        }
    }
}

// ---------------- pull gather (fp16 features, fp32 accumulate) ----------------

template <int D, bool RELU, typename IDX>
__global__ void gather_k(const half_t* __restrict__ hs, const IDX* __restrict__ ssrc,
                         const int* __restrict__ rend, const int* __restrict__ indeg,
                         const float* __restrict__ dinv, const float* __restrict__ bias,
                         float* __restrict__ o, int N) {
    int node = (int)((blockIdx.x * blockDim.x + threadIdx.x) >> 6);
    int lane = threadIdx.x & 63;
    if (node >= N) return;

    int end = rend[node];            // post-fill: row_end
    int deg = indeg[node];
    int start = end - deg;
    float dv = dinv[node];

    if (D == 128) {
        const half_t* hp = hs + 2 * lane;
        half2_t sv = *(const half2_t*)&hp[(size_t)node * 128];   // self loop
        float2 acc;
        acc.x = (float)sv.x;
        acc.y = (float)sv.y;
        for (int base = start; base < end; base += 64) {
            int n = end - base;
            if (n > 64) n = 64;
            int idx = (int)ssrc[(base + lane < end) ? (base + lane) : base];
            int e = 0;
            for (; e + 4 <= n; e += 4) {
                int s0 = __shfl(idx, e + 0);
                int s1 = __shfl(idx, e + 1);
                int s2 = __shfl(idx, e + 2);
                int s3 = __shfl(idx, e + 3);
                half2_t a0 = *(const half2_t*)&hp[(size_t)s0 * 128];
                half2_t a1 = *(const half2_t*)&hp[(size_t)s1 * 128];
                half2_t a2 = *(const half2_t*)&hp[(size_t)s2 * 128];
                half2_t a3 = *(const half2_t*)&hp[(size_t)s3 * 128];
                acc.x += ((float)a0.x + (float)a1.x) + ((float)a2.x + (float)a3.x);
                acc.y += ((float)a0.y + (float)a1.y) + ((float)a2.y + (float)a3.y);
            }
            for (; e < n; ++e) {
                int s0 = __shfl(idx, e);
                half2_t a0 = *(const half2_t*)&hp[(size_t)s0 * 128];
                acc.x += (float)a0.x;
                acc.y += (float)a0.y;
            }
        }
        float2 bb = *(const float2*)&bias[2 * lane];
        acc.x = acc.x * dv + bb.x;
        acc.y = acc.y * dv + bb.y;
        if (RELU) {
            acc.x = fmaxf(acc.x, 0.f);
            acc.y = fmaxf(acc.y, 0.f);
        }
        *(float2*)&o[(size_t)node * 128 + 2 * lane] = acc;
    } else {
        const half_t* hp = hs + lane;
        float acc = (float)hp[(size_t)node * 64];
        for (int base = start; base < end; base += 64) {
            int n = end - base;
            if (n > 64) n = 64;
            int idx = (int)ssrc[(base + lane < end) ? (base + lane) : base];
            int e = 0;
            for (; e + 4 <= n; e += 4) {
                int s0 = __shfl(idx, e + 0);
                int s1 = __shfl(idx, e + 1);
                int s2 = __shfl(idx, e + 2);
                int s3 = __shfl(idx, e + 3);
                float a0 = (float)hp[(size_t)s0 * 64];
                float a1 = (float)hp[(size_t)s1 * 64];
                float a2 = (float)hp[(size_t)s2 * 64];
                float a3 = (float)hp[(size_t)s3 * 64];
                acc += (a0 + a1) + (a2 + a3);
            }
            for (; e < n; ++e) {
                int s0 = __shfl(idx, e);
                acc += (float)hp[(size_t)s0 * 64];
            }
        }
        acc = acc * dv + bias[lane];
        if (RELU) acc = fmaxf(acc, 0.f);
        o[(size_t)node * 64 + lane] = acc;
    }
}

// ---------------- launcher ----------------

extern "C" void kernel_launch(void* const* d_in, const int* in_sizes, int n_in,
                              void* d_out, int out_size, void* d_ws, size_t ws_size,
                              hipStream_t stream) {
    const float* x  = (const float*)d_in[0];
    const int*   ei = (const int*)d_in[1];
    const float* W1 = (const float*)d_in[2];
    const float* b1 = (const float*)d_in[3];
    const float* W2 = (const float*)d_in[4];
    const float* b2 = (const float*)d_in[5];
    float* out = (float*)d_out;

    const int N = in_sizes[0] / 128;
    const int E = in_sizes[1] / 2;
    const int* esrc = ei;
    const int* edst = ei + E;

    // workspace layout
    int* indeg = (int*)d_ws;                          // N
    int* rs    = indeg + N;                           // N (row_start -> row_end)
    int* bsums = rs + N;                              // 64
    unsigned short* ssrc16 = (unsigned short*)(bsums + 64);  // E (uint16)
    int* ssrc32 = (int*)(bsums + 64);                 // E (int32 fallback)
    float* dinv = (float*)((char*)(bsums + 64) + (size_t)E * 4); // N
    half_t* hs1 = (half_t*)(dinv + N);                // N*128 fp16 (reused as hs2)
    float* g1   = (float*)(hs1 + (size_t)N * 128);    // N*128 fp32
    half_t* hs2 = hs1;

    const int nb = (N + 1023) / 1024;
    const int Ggemm1 = (N + 63) / 64;
    const int Gfill  = (E + 511) / 512;

    // degree + dinv + CSR scan
    hipMemsetAsync(indeg, 0, (size_t)N * 4, stream);
    hipLaunchKernelGGL(indeg_k, dim3((E / 4 + 255) / 256), dim3(256), 0, stream, edst, indeg, E);
    hipLaunchKernelGGL(scan1_k, dim3(nb), dim3(256), 0, stream, indeg, rs, bsums, dinv, N);
    hipLaunchKernelGGL(scan3_k, dim3((N + 255) / 256), dim3(256), 0, stream, rs, bsums, nb, N);

    if (N <= 65536) {
        // fused: gemm1 tiles + CSR fill (independent work, one launch)
        hipLaunchKernelGGL((gemm_fill_k<128, unsigned short>),
                           dim3(Ggemm1 + Gfill), dim3(256), 0, stream,
                           x, W1, dinv, hs1, N, Ggemm1, esrc, edst, rs, ssrc16, E);
        hipLaunchKernelGGL((gather_k<128, true, unsigned short>),
                           dim3((N + 3) / 4), dim3(256), 0, stream,
                           hs1, ssrc16, rs, indeg, dinv, b1, g1, N);
        hipLaunchKernelGGL((gemm_tiled_k<64>), dim3((N + 63) / 64), dim3(256), 0, stream,
                           g1, W2, dinv, hs2, N);
        hipLaunchKernelGGL((gather_k<64, false, unsigned short>),
                           dim3((N + 3) / 4), dim3(256), 0, stream,
                           hs2, ssrc16, rs, indeg, dinv, b2, out, N);
    } else {
        hipLaunchKernelGGL((gemm_fill_k<128, int>),
                           dim3(Ggemm1 + Gfill), dim3(256), 0, stream,
                           x, W1, dinv, hs1, N, Ggemm1, esrc, edst, rs, ssrc32, E);
        hipLaunchKernelGGL((gather_k<128, true, int>),
                           dim3((N + 3) / 4), dim3(256), 0, stream,
                           hs1, ssrc32, rs, indeg, dinv, b1, g1, N);
        hipLaunchKernelGGL((gemm_tiled_k<64>), dim3((N + 63) / 64), dim3(256), 0, stream,
                           g1, W2, dinv, hs2, N);
        hipLaunchKernelGGL((gather_k<64, false, int>),
                           dim3((N + 3) / 4), dim3(256), 0, stream,
                           hs2, ssrc32, rs, indeg, dinv, b2, out, N);
    }
}

// Round 7
// 273.518 us; speedup vs baseline: 2.4316x; 1.0197x over previous
//
#include <hip/hip_runtime.h>
#include <hip/hip_fp16.h>

// GCN 2-layer, pull-based CSR gather, fp16 dense intermediates.
// R7 DAG: k1[indeg ∪ gemm1(unscaled)] -> k2[scan1+dinv] -> k3[scan3 ∪ hs*=dinv]
//         -> k4[fill] -> k5[gather1] -> k6[gemm2] -> k7[gather2]

typedef _Float16 half_t;
typedef _Float16 half2_t __attribute__((ext_vector_type(2)));
typedef _Float16 half4_t __attribute__((ext_vector_type(4)));
typedef _Float16 half8_t __attribute__((ext_vector_type(8)));

// ---------------- tiled fp32 GEMM body -> fp16 out ----------------
// BM=64, BK=16, 256 threads, 4x4(+4x4) micro-tile, double-buffered LDS.
// No min-occupancy pledge (R3: (256,4) spilled accumulators to scratch).

template <int BN, bool SCALE>
__device__ __forceinline__ void gemm_body(const float* __restrict__ A,
                                          const float* __restrict__ W,
                                          const float* __restrict__ dinv,
                                          half_t* __restrict__ C, int M, int r0) {
    constexpr int BK = 16, KI = 128 / BK;
    __shared__ float As[2][BK][64 + 4];
    __shared__ float Bs[2][BK][BN];

    const int t = threadIdx.x;
    const int tx = t & 15;
    const int ty = t >> 4;

    const int ar = t >> 2;
    const int ak = (t & 3) * 4;
    const int arow = (r0 + ar < M) ? (r0 + ar) : (M - 1);

    const int br0 = (BN == 128) ? (t >> 5) : (t >> 4);
    const int bc0 = (BN == 128) ? ((t & 31) * 4) : ((t & 15) * 4);

    float4 aR, bR0, bR1;

    aR = *(const float4*)&A[(size_t)arow * 128 + ak];
    bR0 = *(const float4*)&W[(size_t)br0 * BN + bc0];
    if (BN == 128) bR1 = *(const float4*)&W[(size_t)(br0 + 8) * BN + bc0];

    int buf = 0;
    {
        As[buf][ak + 0][ar] = aR.x;
        As[buf][ak + 1][ar] = aR.y;
        As[buf][ak + 2][ar] = aR.z;
        As[buf][ak + 3][ar] = aR.w;
        *(float4*)&Bs[buf][br0][bc0] = bR0;
        if (BN == 128) *(float4*)&Bs[buf][br0 + 8][bc0] = bR1;
    }
    __syncthreads();

    float acc0[4][4], acc1[4][4];
#pragma unroll
    for (int r = 0; r < 4; ++r)
#pragma unroll
        for (int c = 0; c < 4; ++c) { acc0[r][c] = 0.f; acc1[r][c] = 0.f; }

#pragma unroll 1
    for (int it = 0; it < KI; ++it) {
        const int k0n = (it + 1) * BK;
        if (it + 1 < KI) {
            aR = *(const float4*)&A[(size_t)arow * 128 + k0n + ak];
            bR0 = *(const float4*)&W[(size_t)(k0n + br0) * BN + bc0];
            if (BN == 128) bR1 = *(const float4*)&W[(size_t)(k0n + br0 + 8) * BN + bc0];
        }
#pragma unroll
        for (int k = 0; k < BK; ++k) {
            float4 av = *(const float4*)&As[buf][k][ty * 4];
            float4 b0 = *(const float4*)&Bs[buf][k][tx * 4];
            float a_[4] = {av.x, av.y, av.z, av.w};
            float b0_[4] = {b0.x, b0.y, b0.z, b0.w};
            if (BN == 128) {
                float4 b1 = *(const float4*)&Bs[buf][k][64 + tx * 4];
                float b1_[4] = {b1.x, b1.y, b1.z, b1.w};
#pragma unroll
                for (int r = 0; r < 4; ++r)
#pragma unroll
                    for (int c = 0; c < 4; ++c) {
                        acc0[r][c] = fmaf(a_[r], b0_[c], acc0[r][c]);
                        acc1[r][c] = fmaf(a_[r], b1_[c], acc1[r][c]);
                    }
            } else {
#pragma unroll
                for (int r = 0; r < 4; ++r)
#pragma unroll
                    for (int c = 0; c < 4; ++c)
                        acc0[r][c] = fmaf(a_[r], b0_[c], acc0[r][c]);
            }
        }
        if (it + 1 < KI) {
            int nb = buf ^ 1;
            As[nb][ak + 0][ar] = aR.x;
            As[nb][ak + 1][ar] = aR.y;
            As[nb][ak + 2][ar] = aR.z;
            As[nb][ak + 3][ar] = aR.w;
            *(float4*)&Bs[nb][br0][bc0] = bR0;
            if (BN == 128) *(float4*)&Bs[nb][br0 + 8][bc0] = bR1;
            __syncthreads();
            buf = nb;
        }
    }

#pragma unroll
    for (int r = 0; r < 4; ++r) {
        int row = r0 + ty * 4 + r;
        if (row < M) {
            float s = SCALE ? dinv[row] : 1.0f;
            half4_t p;
            p.x = (half_t)(acc0[r][0] * s); p.y = (half_t)(acc0[r][1] * s);
            p.z = (half_t)(acc0[r][2] * s); p.w = (half_t)(acc0[r][3] * s);
            *(half4_t*)&C[(size_t)row * BN + tx * 4] = p;
            if (BN == 128) {
                half4_t q;
                q.x = (half_t)(acc1[r][0] * s); q.y = (half_t)(acc1[r][1] * s);
                q.z = (half_t)(acc1[r][2] * s); q.w = (half_t)(acc1[r][3] * s);
                *(half4_t*)&C[(size_t)row * BN + 64 + tx * 4] = q;
            }
        }
    }
}

// ---------------- k1: degree count (int4 atomics) ∪ gemm1 (unscaled) --------

__launch_bounds__(256)
__global__ void deg_gemm_k(const int* __restrict__ edst, int* __restrict__ indeg,
                           int E, int Gdeg,
                           const float* __restrict__ A, const float* __restrict__ W,
                           half_t* __restrict__ C, int M) {
    int b = blockIdx.x;
    if (b < Gdeg) {
        int i = b * 256 + threadIdx.x;
        int E4 = E >> 2;
        if (i < E4) {
            int4 d = ((const int4*)edst)[i];
            atomicAdd(&indeg[d.x], 1);
            atomicAdd(&indeg[d.y], 1);
            atomicAdd(&indeg[d.z], 1);
            atomicAdd(&indeg[d.w], 1);
        }
        int r = (E4 << 2) + i;
        if (r < E) atomicAdd(&indeg[edst[r]], 1);
    } else {
        gemm_body<128, false>(A, W, nullptr, C, M, (b - Gdeg) * 64);
    }
}

// ---------------- k2: exclusive scan (1024/block) + dinv ----------------

__global__ void scan1_k(const int* __restrict__ in, int* __restrict__ out,
                        int* __restrict__ bsums, float* __restrict__ dinv, int n) {
    __shared__ int lds[256];
    int t = threadIdx.x;
    int base = blockIdx.x * 1024 + t * 4;
    int v0 = 0, v1 = 0, v2 = 0, v3 = 0;
    if (base + 0 < n) v0 = in[base + 0];
    if (base + 1 < n) v1 = in[base + 1];
    if (base + 2 < n) v2 = in[base + 2];
    if (base + 3 < n) v3 = in[base + 3];
    if (base + 0 < n) dinv[base + 0] = rsqrtf(1.0f + (float)v0);
    if (base + 1 < n) dinv[base + 1] = rsqrtf(1.0f + (float)v1);
    if (base + 2 < n) dinv[base + 2] = rsqrtf(1.0f + (float)v2);
    if (base + 3 < n) dinv[base + 3] = rsqrtf(1.0f + (float)v3);
    lds[t] = v0 + v1 + v2 + v3;
    __syncthreads();
    for (int off = 1; off < 256; off <<= 1) {
        int x = (t >= off) ? lds[t - off] : 0;
        __syncthreads();
        lds[t] += x;
        __syncthreads();
    }
    int run = (t > 0) ? lds[t - 1] : 0;
    if (t == 255) bsums[blockIdx.x] = lds[255];
    if (base + 0 < n) { out[base + 0] = run; run += v0; }
    if (base + 1 < n) { out[base + 1] = run; run += v1; }
    if (base + 2 < n) { out[base + 2] = run; run += v2; }
    if (base + 3 < n) { out[base + 3] = run; run += v3; }
}

// ---------------- k3: scan3 fixup ∪ hs *= dinv[node] (in place) -------------

__global__ void scan3_scale_k(int* __restrict__ out, const int* __restrict__ bsums,
                              int nb, int n, int Gs3,
                              half_t* __restrict__ hs, const float* __restrict__ dinv,
                              int n8) {
    int b = blockIdx.x;
    int t = threadIdx.x;
    if (b < Gs3) {
        __shared__ int pre[64];
        if (t < 64) {
            int v = (t < nb) ? bsums[t] : 0;
#pragma unroll
            for (int off = 1; off < 64; off <<= 1) {
                int u = __shfl_up(v, off);
                if (t >= off) v += u;
            }
            pre[t] = v;
        }
        __syncthreads();
        int i = b * 256 + t;
        if (i < n) {
            int blk = i >> 10;
            out[i] += (blk > 0) ? pre[blk - 1] : 0;
        }
    } else {
        int i = (b - Gs3) * 256 + t;      // one half8 (16B) per thread
        if (i < n8) {
            int node = i >> 4;            // 128 halves = 16 half8 per node
            float s = dinv[node];
            half8_t v = ((half8_t*)hs)[i];
#pragma unroll
            for (int j = 0; j < 8; ++j) v[j] = (half_t)((float)v[j] * s);
            ((half8_t*)hs)[i] = v;
        }
    }
}

// ---------------- k4: CSR fill (row_start mutates into inclusive scan) ------

template <typename IDX>
__global__ void fill_k(const int* __restrict__ esrc, const int* __restrict__ edst,
                       int* __restrict__ cur, IDX* __restrict__ ssrc, int E) {
    int i = blockIdx.x * 512 + threadIdx.x;
    if (i < E) {
        int d = edst[i];
        int p = atomicAdd(&cur[d], 1);
        ssrc[p] = (IDX)esrc[i];
    }
    int j = i + 256;
    if (j < E) {
        int d = edst[j];
        int p = atomicAdd(&cur[d], 1);
        ssrc[p] = (IDX)esrc[j];
    }
}

// ---------------- layer-2 GEMM (scaled epilogue) ----------------

template <int BN>
__launch_bounds__(256)
__global__ void gemm_tiled_k(const float* __restrict__ A, const float* __restrict__ W,
                             const float* __restrict__ dinv, half_t* __restrict__ C, int M) {
    gemm_body<BN, true>(A, W, dinv, C, M, blockIdx.x * 64);
}

// ---------------- pull gather (fp16 features, fp32 accumulate) --------------
// rsum = post-fill rs: rsum[i] = inclusive scan of deg -> start=rsum[i-1], end=rsum[i]

template <int D, bool RELU, typename IDX>
__global__ void gather_k(const half_t* __restrict__ hs, const IDX* __restrict__ ssrc,
                         const int* __restrict__ rsum,
                         const float* __restrict__ dinv, const float* __restrict__ bias,
                         float* __restrict__ o, int N) {
    int node = (int)((blockIdx.x * blockDim.x + threadIdx.x) >> 6);
    int lane = threadIdx.x & 63;
    if (node >= N) return;

    int end = rsum[node];
    int start = (node > 0) ? rsum[node - 1] : 0;
    float dv = dinv[node];

    if (D == 128) {
        const half_t* hp = hs + 2 * lane;
        half2_t sv = *(const half2_t*)&hp[(size_t)node * 128];   // self loop
        float2 acc;
        acc.x = (float)sv.x;
        acc.y = (float)sv.y;
        for (int base = start; base < end; base += 64) {
            int n = end - base;
            if (n > 64) n = 64;
            int idx = (int)ssrc[(base + lane < end) ? (base + lane) : base];
            int e = 0;
            for (; e + 4 <= n; e += 4) {
                int s0 = __shfl(idx, e + 0);
                int s1 = __shfl(idx, e + 1);
                int s2 = __shfl(idx, e + 2);
                int s3 = __shfl(idx, e + 3);
                half2_t a0 = *(const half2_t*)&hp[(size_t)s0 * 128];
                half2_t a1 = *(const half2_t*)&hp[(size_t)s1 * 128];
                half2_t a2 = *(const half2_t*)&hp[(size_t)s2 * 128];
                half2_t a3 = *(const half2_t*)&hp[(size_t)s3 * 128];
                acc.x += ((float)a0.x + (float)a1.x) + ((float)a2.x + (float)a3.x);
                acc.y += ((float)a0.y + (float)a1.y) + ((float)a2.y + (float)a3.y);
            }
            for (; e < n; ++e) {
                int s0 = __shfl(idx, e);
                half2_t a0 = *(const half2_t*)&hp[(size_t)s0 * 128];
                acc.x += (float)a0.x;
                acc.y += (float)a0.y;
            }
        }
        float2 bb = *(const float2*)&bias[2 * lane];
        acc.x = acc.x * dv + bb.x;
        acc.y = acc.y * dv + bb.y;
        if (RELU) {
            acc.x = fmaxf(acc.x, 0.f);
            acc.y = fmaxf(acc.y, 0.f);
        }
        *(float2*)&o[(size_t)node * 128 + 2 * lane] = acc;
    } else {
        const half_t* hp = hs + lane;
        float acc = (float)hp[(size_t)node * 64];
        for (int base = start; base < end; base += 64) {
            int n = end - base;
            if (n > 64) n = 64;
            int idx = (int)ssrc[(base + lane < end) ? (base + lane) : base];
            int e = 0;
            for (; e + 4 <= n; e += 4) {
                int s0 = __shfl(idx, e + 0);
                int s1 = __shfl(idx, e + 1);
                int s2 = __shfl(idx, e + 2);
                int s3 = __shfl(idx, e + 3);
                float a0 = (float)hp[(size_t)s0 * 64];
                float a1 = (float)hp[(size_t)s1 * 64];
                float a2 = (float)hp[(size_t)s2 * 64];
                float a3 = (float)hp[(size_t)s3 * 64];
                acc += (a0 + a1) + (a2 + a3);
            }
            for (; e < n; ++e) {
                int s0 = __shfl(idx, e);
                acc += (float)hp[(size_t)s0 * 64];
            }
        }
        acc = acc * dv + bias[lane];
        if (RELU) acc = fmaxf(acc, 0.f);
        o[(size_t)node * 64 + lane] = acc;
    }
}

// ---------------- launcher ----------------

extern "C" void kernel_launch(void* const* d_in, const int* in_sizes, int n_in,
                              void* d_out, int out_size, void* d_ws, size_t ws_size,
                              hipStream_t stream) {
    const float* x  = (const float*)d_in[0];
    const int*   ei = (const int*)d_in[1];
    const float* W1 = (const float*)d_in[2];
    const float* b1 = (const float*)d_in[3];
    const float* W2 = (const float*)d_in[4];
    const float* b2 = (const float*)d_in[5];
    float* out = (float*)d_out;

    const int N = in_sizes[0] / 128;
    const int E = in_sizes[1] / 2;
    const int* esrc = ei;
    const int* edst = ei + E;

    // workspace layout
    int* indeg = (int*)d_ws;                          // N
    int* rs    = indeg + N;                           // N (excl scan -> incl scan)
    int* bsums = rs + N;                              // 64
    unsigned short* ssrc16 = (unsigned short*)(bsums + 64);  // E (uint16)
    int* ssrc32 = (int*)(bsums + 64);                 // E (int32 fallback)
    float* dinv = (float*)((char*)(bsums + 64) + (size_t)E * 4); // N
    half_t* hs1 = (half_t*)(dinv + N);                // N*128 fp16 (reused as hs2)
    float* g1   = (float*)(hs1 + (size_t)N * 128);    // N*128 fp32
    half_t* hs2 = hs1;

    const int nb = (N + 1023) / 1024;
    const int Gdeg   = (E / 4 + 255) / 256;
    const int Ggemm1 = (N + 63) / 64;
    const int Gs3    = (N + 255) / 256;
    const int n8     = N * 16;                        // N*128/8
    const int Gscale = (n8 + 255) / 256;
    const int Gfill  = (E + 511) / 512;

    hipMemsetAsync(indeg, 0, (size_t)N * 4, stream);

    // k1: degree atomics ∪ gemm1 (unscaled fp16 h1)
    hipLaunchKernelGGL(deg_gemm_k, dim3(Gdeg + Ggemm1), dim3(256), 0, stream,
                       edst, indeg, E, Gdeg, x, W1, hs1, N);
    // k2: scan + dinv
    hipLaunchKernelGGL(scan1_k, dim3(nb), dim3(256), 0, stream, indeg, rs, bsums, dinv, N);
    // k3: scan fixup ∪ hs1 *= dinv
    hipLaunchKernelGGL(scan3_scale_k, dim3(Gs3 + Gscale), dim3(256), 0, stream,
                       rs, bsums, nb, N, Gs3, hs1, dinv, n8);

    if (N <= 65536) {
        hipLaunchKernelGGL((fill_k<unsigned short>), dim3(Gfill), dim3(256), 0, stream,
                           esrc, edst, rs, ssrc16, E);
        hipLaunchKernelGGL((gather_k<128, true, unsigned short>),
                           dim3((N + 3) / 4), dim3(256), 0, stream,
                           hs1, ssrc16, rs, dinv, b1, g1, N);
        hipLaunchKernelGGL((gemm_tiled_k<64>), dim3((N + 63) / 64), dim3(256), 0, stream,
                           g1, W2, dinv, hs2, N);
        hipLaunchKernelGGL((gather_k<64, false, unsigned short>),
                           dim3((N + 3) / 4), dim3(256), 0, stream,
                           hs2, ssrc16, rs, dinv, b2, out, N);
    } else {
        hipLaunchKernelGGL((fill_k<int>), dim3(Gfill), dim3(256), 0, stream,
                           esrc, edst, rs, ssrc32, E);
        hipLaunchKernelGGL((gather_k<128, true, int>),
                           dim3((N + 3) / 4), dim3(256), 0, stream,
                           hs1, ssrc32, rs, dinv, b1, g1, N);
        hipLaunchKernelGGL((gemm_tiled_k<64>), dim3((N + 63) / 64), dim3(256), 0, stream,
                           g1, W2, dinv, hs2, N);
        hipLaunchKernelGGL((gather_k<64, false, int>),
                           dim3((N + 3) / 4), dim3(256), 0, stream,
                           hs2, ssrc32, rs, dinv, b2, out, N);
    }
}

// Round 8
// 269.959 us; speedup vs baseline: 2.4636x; 1.0132x over previous
//
#include <hip/hip_runtime.h>
#include <hip/hip_fp16.h>

// GCN 2-layer, pull-based CSR gather, fp16 dense intermediates.
// R8: 4-way-split atomic counters (deg4/cur4, class=(e>>2)&3) to cut
// same-address RMW serialization 16->4; gemm1 LDS shrunk to 12.5KB (BK=8)
// so the fused degree blocks reach full wave occupancy.

typedef _Float16 half_t;
typedef _Float16 half2_t __attribute__((ext_vector_type(2)));
typedef _Float16 half4_t __attribute__((ext_vector_type(4)));
typedef _Float16 half8_t __attribute__((ext_vector_type(8)));

// ---------------- gemm1 body: BK=8 double-buffered, 12.5 KB LDS -------------
// [M,128]@[128,128] -> fp16, unscaled epilogue. 4x4+4x4 micro-tile.

__device__ __forceinline__ void gemm128_bk8(const float* __restrict__ A,
                                            const float* __restrict__ W,
                                            half_t* __restrict__ C, int M, int r0) {
    __shared__ float As[2][8][68];
    __shared__ float Bs[2][8][128];

    const int t = threadIdx.x;
    const int tx = t & 15;
    const int ty = t >> 4;

    const int ar = t >> 2;            // row 0..63
    const int ak = (t & 3) * 2;       // col pair 0,2,4,6
    const int arow = (r0 + ar < M) ? (r0 + ar) : (M - 1);
    const int br = t >> 5;            // 0..7
    const int bc = (t & 31) * 4;      // 0..124

    float2 aR;
    float4 bR;
    aR = *(const float2*)&A[(size_t)arow * 128 + ak];
    bR = *(const float4*)&W[(size_t)br * 128 + bc];

    int buf = 0;
    As[buf][ak + 0][ar] = aR.x;
    As[buf][ak + 1][ar] = aR.y;
    *(float4*)&Bs[buf][br][bc] = bR;
    __syncthreads();

    float acc0[4][4], acc1[4][4];
#pragma unroll
    for (int r = 0; r < 4; ++r)
#pragma unroll
        for (int c = 0; c < 4; ++c) { acc0[r][c] = 0.f; acc1[r][c] = 0.f; }

#pragma unroll 1
    for (int it = 0; it < 16; ++it) {
        if (it + 1 < 16) {
            const int k0n = (it + 1) * 8;
            aR = *(const float2*)&A[(size_t)arow * 128 + k0n + ak];
            bR = *(const float4*)&W[(size_t)(k0n + br) * 128 + bc];
        }
#pragma unroll
        for (int k = 0; k < 8; ++k) {
            float4 av = *(const float4*)&As[buf][k][ty * 4];
            float4 b0 = *(const float4*)&Bs[buf][k][tx * 4];
            float4 b1 = *(const float4*)&Bs[buf][k][64 + tx * 4];
            float a_[4] = {av.x, av.y, av.z, av.w};
            float b0_[4] = {b0.x, b0.y, b0.z, b0.w};
            float b1_[4] = {b1.x, b1.y, b1.z, b1.w};
#pragma unroll
            for (int r = 0; r < 4; ++r)
#pragma unroll
                for (int c = 0; c < 4; ++c) {
                    acc0[r][c] = fmaf(a_[r], b0_[c], acc0[r][c]);
                    acc1[r][c] = fmaf(a_[r], b1_[c], acc1[r][c]);
                }
        }
        if (it + 1 < 16) {
            int nb = buf ^ 1;
            As[nb][ak + 0][ar] = aR.x;
            As[nb][ak + 1][ar] = aR.y;
            *(float4*)&Bs[nb][br][bc] = bR;
            __syncthreads();
            buf = nb;
        }
    }

#pragma unroll
    for (int r = 0; r < 4; ++r) {
        int row = r0 + ty * 4 + r;
        if (row < M) {
            half4_t p;
            p.x = (half_t)acc0[r][0]; p.y = (half_t)acc0[r][1];
            p.z = (half_t)acc0[r][2]; p.w = (half_t)acc0[r][3];
            *(half4_t*)&C[(size_t)row * 128 + tx * 4] = p;
            half4_t q;
            q.x = (half_t)acc1[r][0]; q.y = (half_t)acc1[r][1];
            q.z = (half_t)acc1[r][2]; q.w = (half_t)acc1[r][3];
            *(half4_t*)&C[(size_t)row * 128 + 64 + tx * 4] = q;
        }
    }
}

// ---------------- k1: 4-way degree count ∪ gemm1 ----------------

__launch_bounds__(256)
__global__ void deg_gemm_k(const int* __restrict__ edst, int* __restrict__ deg4,
                           int E, int N, int Gdeg,
                           const float* __restrict__ A, const float* __restrict__ W,
                           half_t* __restrict__ C, int M) {
    int b = blockIdx.x;
    if (b < Gdeg) {
        int i = b * 256 + threadIdx.x;
        int E4 = E >> 2;
        if (i < E4) {
            int4 d = ((const int4*)edst)[i];
            int* cnt = deg4 + (size_t)(i & 3) * N;   // class (e>>2)&3 == i&3
            atomicAdd(&cnt[d.x], 1);
            atomicAdd(&cnt[d.y], 1);
            atomicAdd(&cnt[d.z], 1);
            atomicAdd(&cnt[d.w], 1);
        }
        int r = (E4 << 2) + i;
        if (r < E) atomicAdd(&deg4[(size_t)((r >> 2) & 3) * N + edst[r]], 1);
    } else {
        gemm128_bk8(A, W, C, M, (b - Gdeg) * 64);
    }
}

// ---------------- k2: sum 4 copies, dinv, exclusive scan, cursor bases ------

__global__ void scan1_k(const int* __restrict__ deg4, int* __restrict__ rs,
                        int* __restrict__ cur4, int* __restrict__ bsums,
                        float* __restrict__ dinv, int n) {
    __shared__ int lds[256];
    int t = threadIdx.x;
    int base = blockIdx.x * 1024 + t * 4;
    int d[4][4];                      // [j][class]
    int tot[4] = {0, 0, 0, 0};
#pragma unroll
    for (int j = 0; j < 4; ++j) {
        int node = base + j;
        if (node < n) {
            d[j][0] = deg4[node];
            d[j][1] = deg4[(size_t)n + node];
            d[j][2] = deg4[(size_t)2 * n + node];
            d[j][3] = deg4[(size_t)3 * n + node];
            tot[j] = d[j][0] + d[j][1] + d[j][2] + d[j][3];
            dinv[node] = rsqrtf(1.0f + (float)tot[j]);
        }
    }
    lds[t] = tot[0] + tot[1] + tot[2] + tot[3];
    __syncthreads();
    for (int off = 1; off < 256; off <<= 1) {
        int x = (t >= off) ? lds[t - off] : 0;
        __syncthreads();
        lds[t] += x;
        __syncthreads();
    }
    int run = (t > 0) ? lds[t - 1] : 0;
    if (t == 255) bsums[blockIdx.x] = lds[255];
#pragma unroll
    for (int j = 0; j < 4; ++j) {
        int node = base + j;
        if (node < n) {
            rs[node] = run;
            cur4[node] = run;
            cur4[(size_t)n + node] = run + d[j][0];
            cur4[(size_t)2 * n + node] = run + d[j][0] + d[j][1];
            cur4[(size_t)3 * n + node] = run + d[j][0] + d[j][1] + d[j][2];
            run += tot[j];
        }
    }
}

// ---------------- k3: scan fixup (rs + cur4) ∪ hs *= dinv -------------------

__global__ void scan3_scale_k(int* __restrict__ rs, int* __restrict__ cur4,
                              const int* __restrict__ bsums,
                              int nb, int n, int Gs3,
                              half_t* __restrict__ hs, const float* __restrict__ dinv,
                              int n8) {
    int b = blockIdx.x;
    int t = threadIdx.x;
    if (b < Gs3) {
        __shared__ int pre[64];
        if (t < 64) {
            int v = (t < nb) ? bsums[t] : 0;
#pragma unroll
            for (int off = 1; off < 64; off <<= 1) {
                int u = __shfl_up(v, off);
                if (t >= off) v += u;
            }
            pre[t] = v;
        }
        __syncthreads();
        int i = b * 256 + t;
        if (i < n) {
            int blk = i >> 10;
            int add = (blk > 0) ? pre[blk - 1] : 0;
            rs[i] += add;
            cur4[i] += add;
            cur4[(size_t)n + i] += add;
            cur4[(size_t)2 * n + i] += add;
            cur4[(size_t)3 * n + i] += add;
        }
    } else {
        int i = (b - Gs3) * 256 + t;      // one half8 (16B) per thread
        if (i < n8) {
            int node = i >> 4;            // 128 halves = 16 half8 per node
            float s = dinv[node];
            half8_t v = ((half8_t*)hs)[i];
#pragma unroll
            for (int j = 0; j < 8; ++j) v[j] = (half_t)((float)v[j] * s);
            ((half8_t*)hs)[i] = v;
        }
    }
}

// ---------------- k4: CSR fill via 4-way cursors ----------------

template <typename IDX>
__global__ void fill_k(const int* __restrict__ esrc, const int* __restrict__ edst,
                       int* __restrict__ cur4, IDX* __restrict__ ssrc, int E, int N) {
    int i = blockIdx.x * 512 + threadIdx.x;
    if (i < E) {
        int d = edst[i];
        int p = atomicAdd(&cur4[(size_t)((i >> 2) & 3) * N + d], 1);
        ssrc[p] = (IDX)esrc[i];
    }
    int j = i + 256;
    if (j < E) {
        int d = edst[j];
        int p = atomicAdd(&cur4[(size_t)((j >> 2) & 3) * N + d], 1);
        ssrc[p] = (IDX)esrc[j];
    }
}

// ---------------- layer-2 GEMM: BK=16 double-buffered, scaled epilogue ------

__launch_bounds__(256)
__global__ void gemm2_k(const float* __restrict__ A, const float* __restrict__ W,
                        const float* __restrict__ dinv, half_t* __restrict__ C, int M) {
    constexpr int BN = 64, BK = 16, KI = 128 / BK;
    __shared__ float As[2][BK][64 + 4];
    __shared__ float Bs[2][BK][BN];

    const int t = threadIdx.x;
    const int tx = t & 15;
    const int ty = t >> 4;
    const int r0 = blockIdx.x * 64;

    const int ar = t >> 2;
    const int ak = (t & 3) * 4;
    const int arow = (r0 + ar < M) ? (r0 + ar) : (M - 1);
    const int br0 = t >> 4;
    const int bc0 = (t & 15) * 4;

    float4 aR, bR0;
    aR = *(const float4*)&A[(size_t)arow * 128 + ak];
    bR0 = *(const float4*)&W[(size_t)br0 * BN + bc0];

    int buf = 0;
    As[buf][ak + 0][ar] = aR.x;
    As[buf][ak + 1][ar] = aR.y;
    As[buf][ak + 2][ar] = aR.z;
    As[buf][ak + 3][ar] = aR.w;
    *(float4*)&Bs[buf][br0][bc0] = bR0;
    __syncthreads();

    float acc0[4][4];
#pragma unroll
    for (int r = 0; r < 4; ++r)
#pragma unroll
        for (int c = 0; c < 4; ++c) acc0[r][c] = 0.f;

#pragma unroll 1
    for (int it = 0; it < KI; ++it) {
        const int k0n = (it + 1) * BK;
        if (it + 1 < KI) {
            aR = *(const float4*)&A[(size_t)arow * 128 + k0n + ak];
            bR0 = *(const float4*)&W[(size_t)(k0n + br0) * BN + bc0];
        }
#pragma unroll
        for (int k = 0; k < BK; ++k) {
            float4 av = *(const float4*)&As[buf][k][ty * 4];
            float4 b0 = *(const float4*)&Bs[buf][k][tx * 4];
            float a_[4] = {av.x, av.y, av.z, av.w};
            float b0_[4] = {b0.x, b0.y, b0.z, b0.w};
#pragma unroll
            for (int r = 0; r < 4; ++r)
#pragma unroll
                for (int c = 0; c < 4; ++c)
                    acc0[r][c] = fmaf(a_[r], b0_[c], acc0[r][c]);
        }
        if (it + 1 < KI) {
            int nb = buf ^ 1;
            As[nb][ak + 0][ar] = aR.x;
            As[nb][ak + 1][ar] = aR.y;
            As[nb][ak + 2][ar] = aR.z;
            As[nb][ak + 3][ar] = aR.w;
            *(float4*)&Bs[nb][br0][bc0] = bR0;
            __syncthreads();
            buf = nb;
        }
    }

#pragma unroll
    for (int r = 0; r < 4; ++r) {
        int row = r0 + ty * 4 + r;
        if (row < M) {
            float s = dinv[row];
            half4_t p;
            p.x = (half_t)(acc0[r][0] * s); p.y = (half_t)(acc0[r][1] * s);
            p.z = (half_t)(acc0[r][2] * s); p.w = (half_t)(acc0[r][3] * s);
            *(half4_t*)&C[(size_t)row * BN + tx * 4] = p;
        }
    }
}

// ---------------- pull gather (fp16 features, fp32 accumulate) --------------
// rs is a pure exclusive scan: start=rs[node], end=rs[node+1] (E for last).

template <int D, bool RELU, typename IDX>
__global__ void gather_k(const half_t* __restrict__ hs, const IDX* __restrict__ ssrc,
                         const int* __restrict__ rs,
                         const float* __restrict__ dinv, const float* __restrict__ bias,
                         float* __restrict__ o, int N, int E) {
    int node = (int)((blockIdx.x * blockDim.x + threadIdx.x) >> 6);
    int lane = threadIdx.x & 63;
    if (node >= N) return;

    int start = rs[node];
    int end = (node + 1 < N) ? rs[node + 1] : E;
    float dv = dinv[node];

    if (D == 128) {
        const half_t* hp = hs + 2 * lane;
        half2_t sv = *(const half2_t*)&hp[(size_t)node * 128];   // self loop
        float2 acc;
        acc.x = (float)sv.x;
        acc.y = (float)sv.y;
        for (int base = start; base < end; base += 64) {
            int n = end - base;
            if (n > 64) n = 64;
            int idx = (int)ssrc[(base + lane < end) ? (base + lane) : base];
            int e = 0;
            for (; e + 4 <= n; e += 4) {
                int s0 = __shfl(idx, e + 0);
                int s1 = __shfl(idx, e + 1);
                int s2 = __shfl(idx, e + 2);
                int s3 = __shfl(idx, e + 3);
                half2_t a0 = *(const half2_t*)&hp[(size_t)s0 * 128];
                half2_t a1 = *(const half2_t*)&hp[(size_t)s1 * 128];
                half2_t a2 = *(const half2_t*)&hp[(size_t)s2 * 128];
                half2_t a3 = *(const half2_t*)&hp[(size_t)s3 * 128];
                acc.x += ((float)a0.x + (float)a1.x) + ((float)a2.x + (float)a3.x);
                acc.y += ((float)a0.y + (float)a1.y) + ((float)a2.y + (float)a3.y);
            }
            for (; e < n; ++e) {
                int s0 = __shfl(idx, e);
                half2_t a0 = *(const half2_t*)&hp[(size_t)s0 * 128];
                acc.x += (float)a0.x;
                acc.y += (float)a0.y;
            }
        }
        float2 bb = *(const float2*)&bias[2 * lane];
        acc.x = acc.x * dv + bb.x;
        acc.y = acc.y * dv + bb.y;
        if (RELU) {
            acc.x = fmaxf(acc.x, 0.f);
            acc.y = fmaxf(acc.y, 0.f);
        }
        *(float2*)&o[(size_t)node * 128 + 2 * lane] = acc;
    } else {
        const half_t* hp = hs + lane;
        float acc = (float)hp[(size_t)node * 64];
        for (int base = start; base < end; base += 64) {
            int n = end - base;
            if (n > 64) n = 64;
            int idx = (int)ssrc[(base + lane < end) ? (base + lane) : base];
            int e = 0;
            for (; e + 4 <= n; e += 4) {
                int s0 = __shfl(idx, e + 0);
                int s1 = __shfl(idx, e + 1);
                int s2 = __shfl(idx, e + 2);
                int s3 = __shfl(idx, e + 3);
                float a0 = (float)hp[(size_t)s0 * 64];
                float a1 = (float)hp[(size_t)s1 * 64];
                float a2 = (float)hp[(size_t)s2 * 64];
                float a3 = (float)hp[(size_t)s3 * 64];
                acc += (a0 + a1) + (a2 + a3);
            }
            for (; e < n; ++e) {
                int s0 = __shfl(idx, e);
                acc += (float)hp[(size_t)s0 * 64];
            }
        }
        acc = acc * dv + bias[lane];
        if (RELU) acc = fmaxf(acc, 0.f);
        o[(size_t)node * 64 + lane] = acc;
    }
}

// ---------------- launcher ----------------

extern "C" void kernel_launch(void* const* d_in, const int* in_sizes, int n_in,
                              void* d_out, int out_size, void* d_ws, size_t ws_size,
                              hipStream_t stream) {
    const float* x  = (const float*)d_in[0];
    const int*   ei = (const int*)d_in[1];
    const float* W1 = (const float*)d_in[2];
    const float* b1 = (const float*)d_in[3];
    const float* W2 = (const float*)d_in[4];
    const float* b2 = (const float*)d_in[5];
    float* out = (float*)d_out;

    const int N = in_sizes[0] / 128;
    const int E = in_sizes[1] / 2;
    const int* esrc = ei;
    const int* edst = ei + E;

    // workspace layout
    int* deg4  = (int*)d_ws;                          // 4N
    int* cur4  = deg4 + (size_t)4 * N;                // 4N
    int* rs    = cur4 + (size_t)4 * N;                // N
    int* bsums = rs + N;                              // 64
    unsigned short* ssrc16 = (unsigned short*)(bsums + 64);  // E (uint16)
    int* ssrc32 = (int*)(bsums + 64);                 // E (int32 fallback)
    float* dinv = (float*)((char*)(bsums + 64) + (size_t)E * 4); // N
    half_t* hs1 = (half_t*)(dinv + N);                // N*128 fp16 (reused as hs2)
    float* g1   = (float*)(hs1 + (size_t)N * 128);    // N*128 fp32
    half_t* hs2 = hs1;

    const int nb = (N + 1023) / 1024;
    const int Gdeg   = ((E >> 2) + 255) / 256;
    const int Ggemm1 = (N + 63) / 64;
    const int Gs3    = (N + 255) / 256;
    const int n8     = N * 16;                        // N*128/8
    const int Gscale = (n8 + 255) / 256;
    const int Gfill  = (E + 511) / 512;

    hipMemsetAsync(deg4, 0, (size_t)4 * N * 4, stream);

    // k1: 4-way degree atomics ∪ gemm1 (unscaled fp16 h1, 12.5KB LDS)
    hipLaunchKernelGGL(deg_gemm_k, dim3(Gdeg + Ggemm1), dim3(256), 0, stream,
                       edst, deg4, E, N, Gdeg, x, W1, hs1, N);
    // k2: sum copies + dinv + exclusive scan + per-class cursor bases
    hipLaunchKernelGGL(scan1_k, dim3(nb), dim3(256), 0, stream,
                       deg4, rs, cur4, bsums, dinv, N);
    // k3: scan fixup (rs + cur4) ∪ hs1 *= dinv
    hipLaunchKernelGGL(scan3_scale_k, dim3(Gs3 + Gscale), dim3(256), 0, stream,
                       rs, cur4, bsums, nb, N, Gs3, hs1, dinv, n8);

    if (N <= 65536) {
        hipLaunchKernelGGL((fill_k<unsigned short>), dim3(Gfill), dim3(256), 0, stream,
                           esrc, edst, cur4, ssrc16, E, N);
        hipLaunchKernelGGL((gather_k<128, true, unsigned short>),
                           dim3((N + 3) / 4), dim3(256), 0, stream,
                           hs1, ssrc16, rs, dinv, b1, g1, N, E);
        hipLaunchKernelGGL(gemm2_k, dim3((N + 63) / 64), dim3(256), 0, stream,
                           g1, W2, dinv, hs2, N);
        hipLaunchKernelGGL((gather_k<64, false, unsigned short>),
                           dim3((N + 3) / 4), dim3(256), 0, stream,
                           hs2, ssrc16, rs, dinv, b2, out, N, E);
    } else {
        hipLaunchKernelGGL((fill_k<int>), dim3(Gfill), dim3(256), 0, stream,
                           esrc, edst, cur4, ssrc32, E, N);
        hipLaunchKernelGGL((gather_k<128, true, int>),
                           dim3((N + 3) / 4), dim3(256), 0, stream,
                           hs1, ssrc32, rs, dinv, b1, g1, N, E);
        hipLaunchKernelGGL(gemm2_k, dim3((N + 63) / 64), dim3(256), 0, stream,
                           g1, W2, dinv, hs2, N);
        hipLaunchKernelGGL((gather_k<64, false, int>),
                           dim3((N + 3) / 4), dim3(256), 0, stream,
                           hs2, ssrc32, rs, dinv, b2, out, N, E);
    }
}